// Round 6
// baseline (653.387 us; speedup 1.0000x reference)
//
#include <hip/hip_runtime.h>
#include <math.h>

#define BB 256
#define TT 512
#define KK 128

typedef float v2f __attribute__((ext_vector_type(2)));

template<int CTRL>
__device__ __forceinline__ int dpp_i(int x) {
  return __builtin_amdgcn_update_dpp(x, x, CTRL, 0xF, 0xF, true);
}
template<int CTRL>
__device__ __forceinline__ float dpp_f(float x) {
  return __int_as_float(dpp_i<CTRL>(__float_as_int(x)));
}
template<int CTRL>
__device__ __forceinline__ v2f dpp_v2(v2f x) {
  v2f r; r.x = dpp_f<CTRL>(x.x); r.y = dpp_f<CTRL>(x.y); return r;
}
__device__ __forceinline__ float swz16_f(float x) {
  return __int_as_float(__builtin_amdgcn_ds_swizzle(__float_as_int(x), 0x401F));
}
// barrier draining LDS only — global prefetch/stores stay in flight
#define BARRIER_LGKM() asm volatile("s_waitcnt lgkmcnt(0)\ns_barrier" ::: "memory")

// DPP: 0xB1 quad_perm xor1 (exact), 0x4E quad_perm xor2 (exact),
// 0x141 row_half_mirror (==xor4 once quad-uniform), 0x140 row_mirror (==xor8 once 8-uniform)

__global__ void prep_trans(const float* __restrict__ trans, float* __restrict__ transG) {
  int idx = blockIdx.x * 256 + threadIdx.x;   // 0..16383
  int i = idx >> 7, j = idx & 127;
  transG[j * KK + i] = trans[idx];            // transG[j][i] = trans[i][j]
}

__global__ __launch_bounds__(128, 1) void crf_main(
    const float* __restrict__ logits,     // [B,T,K]
    const int* __restrict__ labels,       // [B,T]
    const int* __restrict__ seq_lens,     // [B]
    const float* __restrict__ trans,      // [K,K]
    float* __restrict__ pred_out,         // [B,T] as float (d_out+1)
    float* __restrict__ negll,            // [B] in ws
    float* __restrict__ ahist,            // [B,T,K] exact viterbi alphas in ws
    const float* __restrict__ transG)     // [K,K] transposed trans in ws
{
  const int tid = threadIdx.x;          // 0..127
  const int w = tid >> 6;               // wave 0/1 : rows 64w..64w+63
  const int l = tid & 63;
  const int rg = l & 3;                 // row subgroup
  const int cgi = l >> 2;               // col group 0..15
  const int j0 = cgi * 8;               // my 8 cols
  const int r0 = w * 64 + rg * 16;      // my 16 rows
  const bool isV = blockIdx.x < BB;
  const int b = isV ? blockIdx.x : (blockIdx.x - BB);
  const int L = seq_lens[b];

  __shared__ __align__(16) float Pe[2][2][KK + 8];  // [buf][wave][col] partials
  __shared__ float wmS[2];
  __shared__ __align__(16) float avf[KK];
  __shared__ unsigned char tags[TT];
  __shared__ float redS[4];
  __shared__ int last_s;

  // W block in registers: 16 rows x 8 cols (raw for V, exp for F)
  v2f tw[16][4];
#pragma unroll
  for (int rr = 0; rr < 16; ++rr) {
    float4 t0 = *(const float4*)&trans[(r0 + rr) * KK + j0];
    float4 t1 = *(const float4*)&trans[(r0 + rr) * KK + j0 + 4];
    if (isV) {
      tw[rr][0] = (v2f){t0.x, t0.y}; tw[rr][1] = (v2f){t0.z, t0.w};
      tw[rr][2] = (v2f){t1.x, t1.y}; tw[rr][3] = (v2f){t1.z, t1.w};
    } else {
      tw[rr][0] = (v2f){__expf(t0.x), __expf(t0.y)};
      tw[rr][1] = (v2f){__expf(t0.z), __expf(t0.w)};
      tw[rr][2] = (v2f){__expf(t1.x), __expf(t1.y)};
      tw[rr][3] = (v2f){__expf(t1.z), __expf(t1.w)};
    }
  }

  // init partial buffers so reconstruct of "alpha_0" works generically
  {
    float l0 = logits[(size_t)b * TT * KK + tid];
    if (isV) {
      Pe[0][0][tid] = l0;            // max(l0, -inf) = l0
      Pe[0][1][tid] = -3.4e38f;
    } else {
      Pe[0][0][tid] = __expf(l0);    // sum(e^l0, 0) = e^l0
      Pe[0][1][tid] = 0.0f;
    }
    if (tid < 2) wmS[tid] = 1.0f;
  }

  // emit prefetch, 2-step chunks: 8 floats (my cols) per step
  float4 emC[2][2], emN[2][2];
#pragma unroll
  for (int s = 0; s < 2; ++s) {
    int t2 = 1 + s; if (t2 > L - 1) t2 = (L > 1) ? (L - 1) : 0;
    emC[s][0] = *(const float4*)&logits[((size_t)b * TT + t2) * KK + j0];
    emC[s][1] = *(const float4*)&logits[((size_t)b * TT + t2) * KK + j0 + 4];
  }
  __syncthreads();

  float Cln = 0.0f;
  for (int tc = 1; tc < L; tc += 2) {
#pragma unroll
    for (int s = 0; s < 2; ++s) {
      int t2 = tc + 2 + s; if (t2 > L - 1) t2 = L - 1;
      emN[s][0] = *(const float4*)&logits[((size_t)b * TT + t2) * KK + j0];
      emN[s][1] = *(const float4*)&logits[((size_t)b * TT + t2) * KK + j0 + 4];
    }
    float r = 1.0f;
    if (!isV) {                        // renorm from previous chunk's ev max
      float U = fmaxf(wmS[0], wmS[1]);
      int ex = (__float_as_int(U) >> 23) & 255;
      r = __int_as_float((254 - ex) << 23);     // exact power of 2
      Cln += (float)(ex - 127) * 0.6931471805599453f;
    }
#pragma unroll
    for (int s = 0; s < 2; ++s) {
      const int t = tc + s;
      if (t >= L) break;               // uniform
      const int rb = (t - 1) & 1, wb = t & 1;

      // reconstruct prev state for my 16 rows from both waves' partials
      float a[16];
      {
        const float4* q0 = (const float4*)&Pe[rb][0][r0];
        const float4* q1 = (const float4*)&Pe[rb][1][r0];
#pragma unroll
        for (int k = 0; k < 4; ++k) {
          float4 x = q0[k], y = q1[k];
          if (isV) {
            a[4*k+0] = fmaxf(x.x, y.x); a[4*k+1] = fmaxf(x.y, y.y);
            a[4*k+2] = fmaxf(x.z, y.z); a[4*k+3] = fmaxf(x.w, y.w);
          } else {
            a[4*k+0] = x.x + y.x; a[4*k+1] = x.y + y.y;
            a[4*k+2] = x.z + y.z; a[4*k+3] = x.w + y.w;
          }
        }
      }
      if (isV) {
        // store exact alpha_{t-1} history (cgi==0 lanes: 8 lanes cover 128)
        if (cgi == 0) {
          float* ap = &ahist[((size_t)b * TT + (t - 1)) * KK + r0];
          *(float4*)(ap)      = make_float4(a[0], a[1], a[2], a[3]);
          *(float4*)(ap + 4)  = make_float4(a[4], a[5], a[6], a[7]);
          *(float4*)(ap + 8)  = make_float4(a[8], a[9], a[10], a[11]);
          *(float4*)(ap + 12) = make_float4(a[12], a[13], a[14], a[15]);
        }
        v2f ac0, ac1, ac2, ac3;
#pragma unroll
        for (int rr = 0; rr < 16; ++rr) {
          v2f av = (v2f){a[rr], a[rr]};
          v2f s0 = av + tw[rr][0], s1 = av + tw[rr][1];
          v2f s2 = av + tw[rr][2], s3 = av + tw[rr][3];
          if (rr == 0) { ac0 = s0; ac1 = s1; ac2 = s2; ac3 = s3; }
          else {
            ac0 = __builtin_elementwise_max(ac0, s0);
            ac1 = __builtin_elementwise_max(ac1, s1);
            ac2 = __builtin_elementwise_max(ac2, s2);
            ac3 = __builtin_elementwise_max(ac3, s3);
          }
        }
        ac0 = __builtin_elementwise_max(ac0, dpp_v2<0xB1>(ac0));
        ac1 = __builtin_elementwise_max(ac1, dpp_v2<0xB1>(ac1));
        ac2 = __builtin_elementwise_max(ac2, dpp_v2<0xB1>(ac2));
        ac3 = __builtin_elementwise_max(ac3, dpp_v2<0xB1>(ac3));
        ac0 = __builtin_elementwise_max(ac0, dpp_v2<0x4E>(ac0));
        ac1 = __builtin_elementwise_max(ac1, dpp_v2<0x4E>(ac1));
        ac2 = __builtin_elementwise_max(ac2, dpp_v2<0x4E>(ac2));
        ac3 = __builtin_elementwise_max(ac3, dpp_v2<0x4E>(ac3));
        if (rg == 0) {                 // fold emit into the partial write
          float4 e0 = emC[s][0], e1 = emC[s][1];
          *(float4*)&Pe[wb][w][j0] =
              make_float4(ac0.x + e0.x, ac0.y + e0.y, ac1.x + e0.z, ac1.y + e0.w);
          *(float4*)&Pe[wb][w][j0 + 4] =
              make_float4(ac2.x + e1.x, ac2.y + e1.y, ac3.x + e1.z, ac3.y + e1.w);
        }
      } else {
        // forward-path renorm bookkeeping: wave max of reconstructed ev_{t-1}
        if (s == 1) {
          float lm = fmaxf(fmaxf(fmaxf(a[0], a[1]), fmaxf(a[2], a[3])),
                           fmaxf(fmaxf(a[4], a[5]), fmaxf(a[6], a[7])));
          lm = fmaxf(lm, fmaxf(fmaxf(fmaxf(a[8], a[9]), fmaxf(a[10], a[11])),
                               fmaxf(fmaxf(a[12], a[13]), fmaxf(a[14], a[15]))));
          lm = fmaxf(lm, dpp_f<0xB1>(lm));
          lm = fmaxf(lm, dpp_f<0x4E>(lm));
          if (l == 0) wmS[w] = lm;
        }
        v2f ac0 = {0,0}, ac1 = {0,0}, ac2 = {0,0}, ac3 = {0,0};
#pragma unroll
        for (int rr = 0; rr < 16; ++rr) {
          v2f av = (v2f){a[rr], a[rr]};
          ac0 += av * tw[rr][0]; ac1 += av * tw[rr][1];
          ac2 += av * tw[rr][2]; ac3 += av * tw[rr][3];
        }
        ac0 += dpp_v2<0xB1>(ac0); ac1 += dpp_v2<0xB1>(ac1);
        ac2 += dpp_v2<0xB1>(ac2); ac3 += dpp_v2<0xB1>(ac3);
        ac0 += dpp_v2<0x4E>(ac0); ac1 += dpp_v2<0x4E>(ac1);
        ac2 += dpp_v2<0x4E>(ac2); ac3 += dpp_v2<0x4E>(ac3);
        if (rg == 0) {                 // fold exp(emit)*r into the partial write
          float sc_ = (s == 0) ? r : 1.0f;
          float4 e0 = emC[s][0], e1 = emC[s][1];
          *(float4*)&Pe[wb][w][j0] =
              make_float4(ac0.x * (__expf(e0.x) * sc_), ac0.y * (__expf(e0.y) * sc_),
                          ac1.x * (__expf(e0.z) * sc_), ac1.y * (__expf(e0.w) * sc_));
          *(float4*)&Pe[wb][w][j0 + 4] =
              make_float4(ac2.x * (__expf(e1.x) * sc_), ac2.y * (__expf(e1.y) * sc_),
                          ac3.x * (__expf(e1.z) * sc_), ac3.y * (__expf(e1.w) * sc_));
        }
      }
      BARRIER_LGKM();                  // single 2-wave barrier per step
    }
#pragma unroll
    for (int s = 0; s < 2; ++s) { emC[s][0] = emN[s][0]; emC[s][1] = emN[s][1]; }
  }

  // ---- post-loop: reconstruct final state for my 16 rows ----
  const int fb = (L - 1) & 1;
  float a[16];
  {
    const float4* q0 = (const float4*)&Pe[fb][0][r0];
    const float4* q1 = (const float4*)&Pe[fb][1][r0];
#pragma unroll
    for (int k = 0; k < 4; ++k) {
      float4 x = q0[k], y = q1[k];
      if (isV) {
        a[4*k+0] = fmaxf(x.x, y.x); a[4*k+1] = fmaxf(x.y, y.y);
        a[4*k+2] = fmaxf(x.z, y.z); a[4*k+3] = fmaxf(x.w, y.w);
      } else {
        a[4*k+0] = x.x + y.x; a[4*k+1] = x.y + y.y;
        a[4*k+2] = x.z + y.z; a[4*k+3] = x.w + y.w;
      }
    }
  }

  if (isV) {
    if (cgi == 0) {
      *(float4*)&avf[r0]      = make_float4(a[0], a[1], a[2], a[3]);
      *(float4*)&avf[r0 + 4]  = make_float4(a[4], a[5], a[6], a[7]);
      *(float4*)&avf[r0 + 8]  = make_float4(a[8], a[9], a[10], a[11]);
      *(float4*)&avf[r0 + 12] = make_float4(a[12], a[13], a[14], a[15]);
    }
    __syncthreads();
    if (tid < 64) {                    // argmax of final alpha (first-index ties)
      float2 q = *(const float2*)&avf[2 * tid];
      float v; int idx;
      if (q.x >= q.y) { v = q.x; idx = 2 * tid; } else { v = q.y; idx = 2 * tid + 1; }
#pragma unroll
      for (int mm = 1; mm < 64; mm <<= 1) {
        float ov = __shfl_xor(v, mm);
        int oi = __shfl_xor(idx, mm);
        if (ov > v || (ov == v && oi < idx)) { v = ov; idx = oi; }
      }
      if (tid == 0) last_s = idx;
    }
    __syncthreads();
    const int last = last_s;
    for (int p = tid; p < TT; p += 128)
      if (p >= L - 1) tags[p] = (unsigned char)last;
    __syncthreads();

    // backtrace by wave 0: recompute path argmaxes from exact alphas
    if (tid < 64 && L >= 2) {
      int tag = last;
      int t = L - 1;
      while (t >= 1) {
        const int n = (t < 4) ? t : 4;
        float2 rows[4];
#pragma unroll
        for (int k = 0; k < 4; ++k)
          if (k < n)
            rows[k] = *(const float2*)&ahist[((size_t)b * TT + (t - 1 - k)) * KK + 2 * tid];
#pragma unroll
        for (int k = 0; k < 4; ++k) {
          if (k < n) {
            float2 trow = *(const float2*)&transG[tag * KK + 2 * tid];
            float qx = rows[k].x + trow.x;       // bitwise == forward scores
            float qy = rows[k].y + trow.y;
            float M = fmaxf(qx, qy);
            M = fmaxf(M, dpp_f<0xB1>(M));        // xor1 (exact)
            M = fmaxf(M, dpp_f<0x4E>(M));        // xor2 (exact)
            M = fmaxf(M, dpp_f<0x141>(M));       // xor4 (quad-uniform)
            M = fmaxf(M, dpp_f<0x140>(M));       // xor8 (8-uniform)
            M = fmaxf(M, swz16_f(M));            // xor16
            M = fmaxf(M, __shfl_xor(M, 32));     // xor32
            unsigned long long bx = __ballot(qx == M);
            unsigned long long by = __ballot(qy == M);
            int ix = bx ? ((__ffsll(bx) - 1) << 1) : (1 << 20);
            int iy = by ? ((((__ffsll(by) - 1)) << 1) | 1) : (1 << 20);
            tag = (ix < iy) ? ix : iy;           // first-index tie-break
            if (tid == 0) tags[t - 1 - k] = (unsigned char)tag;
          }
        }
        t -= n;
      }
    }
    __syncthreads();
    for (int p = tid; p < TT; p += 128)
      pred_out[(size_t)b * TT + p] = (float)tags[p];

  } else {
    // log-norm: total = sum of reconstructed final ev
    float ls = ((a[0] + a[1]) + (a[2] + a[3])) + ((a[4] + a[5]) + (a[6] + a[7]));
    ls += ((a[8] + a[9]) + (a[10] + a[11])) + ((a[12] + a[13]) + (a[14] + a[15]));
    ls += dpp_f<0xB1>(ls);
    ls += dpp_f<0x4E>(ls);             // now = this wave's 64-row sum (all lanes)
    if (l == 0) redS[w] = ls;
    // sequence score
    float sc = 0.0f;
    for (int tt2 = tid; tt2 < L; tt2 += 128) {
      int lab = labels[b * TT + tt2];
      sc += logits[((size_t)b * TT + tt2) * KK + lab];
      if (tt2 >= 1) sc += trans[labels[b * TT + tt2 - 1] * KK + lab];
    }
#pragma unroll
    for (int mm = 1; mm < 64; mm <<= 1) sc += __shfl_xor(sc, mm);
    if (l == 0) redS[2 + w] = sc;
    __syncthreads();
    if (tid == 0) {
      float es = redS[0] + redS[1];
      float scf = redS[2] + redS[3];
      negll[b] = (Cln + logf(es)) - scf;
    }
  }
}

__global__ void crf_loss_reduce(const float* __restrict__ negll, float* __restrict__ out) {
  int tid = threadIdx.x;
  float v = negll[tid];
#pragma unroll
  for (int m = 1; m < 64; m <<= 1) v += __shfl_xor(v, m);
  __shared__ float p[4];
  if ((tid & 63) == 0) p[tid >> 6] = v;
  __syncthreads();
  if (tid == 0) out[0] = p[0] + p[1] + p[2] + p[3];
}

extern "C" void kernel_launch(void* const* d_in, const int* in_sizes, int n_in,
                              void* d_out, int out_size, void* d_ws, size_t ws_size,
                              hipStream_t stream) {
  const float* logits   = (const float*)d_in[0];
  const int*   labels   = (const int*)d_in[1];
  const int*   seq_lens = (const int*)d_in[2];
  const float* trans    = (const float*)d_in[3];
  float* out = (float*)d_out;

  float* negll  = (float*)d_ws;                        // 1 KB
  float* transG = (float*)((char*)d_ws + 1024);        // 64 KB transposed trans
  float* ahist  = (float*)((char*)d_ws + 1024 + 65536);// B*T*K fp32 = 67.1 MB

  prep_trans<<<64, 256, 0, stream>>>(trans, transG);
  crf_main<<<2 * BB, 128, 0, stream>>>(logits, labels, seq_lens, trans,
                                       out + 1, negll, ahist, transG);
  crf_loss_reduce<<<1, 256, 0, stream>>>(negll, out);
}